// Round 1
// baseline (905.224 us; speedup 1.0000x reference)
//
#include <hip/hip_runtime.h>
#include <cstdint>

#define NN 8192
#define INC 512
#define HIDC 1024
#define OUTC 256

typedef unsigned short u16;
typedef __attribute__((ext_vector_type(8))) __bf16 bf16x8;
typedef __attribute__((ext_vector_type(4))) float f32x4;

__device__ __forceinline__ u16 f32_to_bf16(float f) {
  union { float f; unsigned u; } c; c.f = f;
  unsigned u = c.u;
  u += 0x7fffu + ((u >> 16) & 1u);   // round-to-nearest-even
  return (u16)(u >> 16);
}

// async global->LDS, 16B/lane. LDS dest is wave-uniform base + lane*16.
__device__ __forceinline__ void async_copy16(const void* g, void* l) {
  typedef __attribute__((address_space(1))) const char gch;
  typedef __attribute__((address_space(3))) char lch;
  __builtin_amdgcn_global_load_lds((gch*)(uint64_t)(uintptr_t)g,
                                   (lch*)(uint32_t)(uintptr_t)l, 16, 0, 0);
}

// deg[i] = sum_j edge[i][j]; isq[i] = deg>0 ? 1/sqrt(deg) : 0
__global__ __launch_bounds__(256) void rowsum_k(const float* __restrict__ edge,
                                                float* __restrict__ isq) {
  __shared__ float red[4];
  const int row = blockIdx.x;
  const float4* e4 = (const float4*)(edge + (size_t)row * NN);
  float s = 0.f;
#pragma unroll
  for (int it = 0; it < NN / 4 / 256; ++it) {
    float4 v = e4[it * 256 + threadIdx.x];
    s += (v.x + v.y) + (v.z + v.w);
  }
  for (int off = 32; off > 0; off >>= 1) s += __shfl_down(s, off, 64);
  if ((threadIdx.x & 63) == 0) red[threadIdx.x >> 6] = s;
  __syncthreads();
  if (threadIdx.x == 0) {
    float t = (red[0] + red[1]) + (red[2] + red[3]);
    isq[row] = (t > 0.f) ? (1.0f / sqrtf(t)) : 0.f;
  }
}

// Abf[i][j] = bf16( isq[i] * edge[i][j] * isq[j] ), grid (NN/1024, NN)
__global__ __launch_bounds__(256) void normalize_k(const float* __restrict__ edge,
                                                   const float* __restrict__ isq,
                                                   u16* __restrict__ Abf) {
  const int row = blockIdx.y;
  const int c4 = blockIdx.x * 256 + threadIdx.x;  // float4 index within row
  const size_t base = (size_t)row * NN;
  float4 e = ((const float4*)(edge + base))[c4];
  float4 q = ((const float4*)isq)[c4];
  const float ri = isq[row];
  ushort4 o;
  o.x = f32_to_bf16(ri * e.x * q.x);
  o.y = f32_to_bf16(ri * e.y * q.y);
  o.z = f32_to_bf16(ri * e.z * q.z);
  o.w = f32_to_bf16(ri * e.w * q.w);
  ((ushort4*)(Abf + base))[c4] = o;
}

__global__ __launch_bounds__(256) void f2bf_k(const float* __restrict__ in,
                                              u16* __restrict__ out, int n4) {
  int i = blockIdx.x * 256 + threadIdx.x;
  if (i >= n4) return;
  float4 v = ((const float4*)in)[i];
  ushort4 o;
  o.x = f32_to_bf16(v.x);
  o.y = f32_to_bf16(v.y);
  o.z = f32_to_bf16(v.z);
  o.w = f32_to_bf16(v.w);
  ((ushort4*)out)[i] = o;
}

// C[M,N] = act(A[M,K] * B[N,K]^T + bias[row]); A,B bf16 row-major, K%32==0,
// M,N%128==0. m97 structure: 128x128 tile, BK=32, 4 waves, 4x4 16x16x32 MFMA,
// global_load_lds width=16, single-buffered LDS (implicit multi-block overlap).
template <bool RELU, bool BIAS, bool OBF16>
__global__ __launch_bounds__(256) void gemm_bt(const u16* __restrict__ A,
                                               const u16* __restrict__ B,
                                               const float* __restrict__ bias,
                                               void* __restrict__ Cout,
                                               const int M, const int N, const int K) {
  __shared__ __attribute__((aligned(16))) u16 As[128 * 32];
  __shared__ __attribute__((aligned(16))) u16 Bs[128 * 32];
  const int tid = threadIdx.x;
  const int wave = tid >> 6;
  const int lane = tid & 63;
  const size_t row0 = (size_t)blockIdx.y * 128;
  const size_t col0 = (size_t)blockIdx.x * 128;
  const int wm = (wave >> 1) << 6;  // wave quadrant: 64x64
  const int wn = (wave & 1) << 6;

  f32x4 acc[4][4];
  const f32x4 zero = {0.f, 0.f, 0.f, 0.f};
#pragma unroll
  for (int i = 0; i < 4; ++i)
#pragma unroll
    for (int j = 0; j < 4; ++j) acc[i][j] = zero;

  // staging: flat element E = issue*2048 + wave*512 + lane*8; row=E/32 col=E%32
  const int e0 = wave * 512 + lane * 8;
  const int r0 = e0 >> 5;
  const int c0 = e0 & 31;
  const u16* Ab = A + row0 * K + (size_t)r0 * K + c0;
  const u16* Bb = B + col0 * K + (size_t)r0 * K + c0;
  u16* sA0 = &As[wave * 512];
  u16* sA1 = &As[2048 + wave * 512];
  u16* sB0 = &Bs[wave * 512];
  u16* sB1 = &Bs[2048 + wave * 512];
  const size_t K64 = (size_t)64 * K;

  const int fr = lane & 15;    // A: m, B: n  (lane&15)
  const int quad = lane >> 4;  // k = quad*8 + j
  const int aoff = (wm + fr) * 32 + quad * 8;
  const int boff = (wn + fr) * 32 + quad * 8;

  for (int kt = 0; kt < K; kt += 32) {
    async_copy16(Ab + kt, sA0);
    async_copy16(Ab + K64 + kt, sA1);
    async_copy16(Bb + kt, sB0);
    async_copy16(Bb + K64 + kt, sB1);
    __syncthreads();  // drains vmcnt -> LDS visible
    bf16x8 af[4], bfr[4];
#pragma unroll
    for (int i = 0; i < 4; ++i) {
      af[i] = *(const bf16x8*)&As[aoff + i * 512];
      bfr[i] = *(const bf16x8*)&Bs[boff + i * 512];
    }
#pragma unroll
    for (int i = 0; i < 4; ++i)
#pragma unroll
      for (int j = 0; j < 4; ++j)
        acc[i][j] = __builtin_amdgcn_mfma_f32_16x16x32_bf16(af[i], bfr[j], acc[i][j], 0, 0, 0);
    __syncthreads();
  }

  // C/D layout (verified m89/m91): col = lane&15, row = (lane>>4)*4 + reg
#pragma unroll
  for (int i = 0; i < 4; ++i) {
#pragma unroll
    for (int r = 0; r < 4; ++r) {
      const size_t grow = row0 + wm + i * 16 + quad * 4 + r;
      float bv = 0.f;
      if (BIAS) bv = bias[grow];
#pragma unroll
      for (int j = 0; j < 4; ++j) {
        const size_t gcol = col0 + wn + j * 16 + fr;
        float v = acc[i][j][r] + bv;
        if (RELU) v = fmaxf(v, 0.f);
        if (OBF16)
          ((u16*)Cout)[grow * N + gcol] = f32_to_bf16(v);
        else
          ((float*)Cout)[grow * N + gcol] = v;
      }
    }
  }
}

extern "C" void kernel_launch(void* const* d_in, const int* in_sizes, int n_in,
                              void* d_out, int out_size, void* d_ws, size_t ws_size,
                              hipStream_t stream) {
  const float* point = (const float*)d_in[0];
  const float* edge  = (const float*)d_in[1];
  const float* W1    = (const float*)d_in[2];
  const float* b1    = (const float*)d_in[3];
  const float* W2    = (const float*)d_in[4];
  const float* b2    = (const float*)d_in[5];
  float* out = (float*)d_out;

  char* ws = (char*)d_ws;
  size_t off = 0;
  auto alloc = [&](size_t bytes) -> void* {
    void* p = ws + off;
    off += (bytes + 255) & ~(size_t)255;
    return p;
  };
  float* isq  = (float*)alloc((size_t)NN * 4);
  u16* Abf    = (u16*)alloc((size_t)NN * NN * 2);        // 128 MB
  u16* pbf    = (u16*)alloc((size_t)NN * INC * 2);       // 8 MB
  u16* w1bf   = (u16*)alloc((size_t)HIDC * INC * 2);     // 1 MB
  u16* w2bf   = (u16*)alloc((size_t)OUTC * HIDC * 2);    // 0.5 MB
  u16* Ht     = (u16*)alloc((size_t)HIDC * NN * 2);      // 16 MB  (h1^T)
  u16* h2     = (u16*)alloc((size_t)NN * HIDC * 2);      // 16 MB  (relu(A h1))
  u16* O1t    = (u16*)alloc((size_t)OUTC * NN * 2);      // 4 MB   (o1^T)

  rowsum_k<<<NN, 256, 0, stream>>>(edge, isq);
  normalize_k<<<dim3(NN / 1024, NN), 256, 0, stream>>>(edge, isq, Abf);
  f2bf_k<<<(NN * INC / 4) / 256, 256, 0, stream>>>(point, pbf, NN * INC / 4);
  f2bf_k<<<(HIDC * INC / 4) / 256, 256, 0, stream>>>(W1, w1bf, HIDC * INC / 4);
  f2bf_k<<<(OUTC * HIDC / 4) / 256, 256, 0, stream>>>(W2, w2bf, OUTC * HIDC / 4);

  // Ht[c][n] = sum_k W1[c][k] point[n][k] + b1[c]   (h1^T, bf16)
  gemm_bt<false, true, true><<<dim3(NN / 128, HIDC / 128), 256, 0, stream>>>(
      w1bf, pbf, b1, Ht, HIDC, NN, INC);
  // h2[i][c] = relu( sum_j Abf[i][j] Ht[c][j] )     (bf16)
  gemm_bt<true, false, true><<<dim3(HIDC / 128, NN / 128), 256, 0, stream>>>(
      Abf, Ht, nullptr, h2, NN, HIDC, NN);
  // O1t[c2][i] = sum_c W2[c2][c] h2[i][c] + b2[c2]  (o1^T, bf16)
  gemm_bt<false, true, true><<<dim3(NN / 128, OUTC / 128), 256, 0, stream>>>(
      w2bf, h2, b2, O1t, OUTC, NN, HIDC);
  // out[i][c2] = relu( sum_j Abf[i][j] O1t[c2][j] ) (fp32, final output)
  gemm_bt<true, false, false><<<dim3(OUTC / 128, NN / 128), 256, 0, stream>>>(
      Abf, O1t, nullptr, out, NN, OUTC, NN);
}

// Round 2
// 841.312 us; speedup vs baseline: 1.0760x; 1.0760x over previous
//
#include <hip/hip_runtime.h>
#include <cstdint>

#define NN 8192
#define INC 512
#define HIDC 1024
#define OUTC 256

typedef unsigned short u16;
typedef __attribute__((ext_vector_type(8))) __bf16 bf16x8;
typedef __attribute__((ext_vector_type(4))) float f32x4;

__device__ __forceinline__ u16 f32_to_bf16(float f) {
  union { float f; unsigned u; } c; c.f = f;
  unsigned u = c.u;
  u += 0x7fffu + ((u >> 16) & 1u);   // round-to-nearest-even
  return (u16)(u >> 16);
}

// async global->LDS, 16B/lane. LDS dest is wave-uniform base + lane*16.
__device__ __forceinline__ void async_copy16(const void* g, void* l) {
  typedef __attribute__((address_space(1))) const char gch;
  typedef __attribute__((address_space(3))) char lch;
  __builtin_amdgcn_global_load_lds((gch*)(uint64_t)(uintptr_t)g,
                                   (lch*)(uint32_t)(uintptr_t)l, 16, 0, 0);
}

// deg[i] = sum_j edge[i][j]; isq[i] = deg>0 ? 1/sqrt(deg) : 0
__global__ __launch_bounds__(256) void rowsum_k(const float* __restrict__ edge,
                                                float* __restrict__ isq) {
  __shared__ float red[4];
  const int row = blockIdx.x;
  const float4* e4 = (const float4*)(edge + (size_t)row * NN);
  float s = 0.f;
#pragma unroll
  for (int it = 0; it < NN / 4 / 256; ++it) {
    float4 v = e4[it * 256 + threadIdx.x];
    s += (v.x + v.y) + (v.z + v.w);
  }
  for (int off = 32; off > 0; off >>= 1) s += __shfl_down(s, off, 64);
  if ((threadIdx.x & 63) == 0) red[threadIdx.x >> 6] = s;
  __syncthreads();
  if (threadIdx.x == 0) {
    float t = (red[0] + red[1]) + (red[2] + red[3]);
    isq[row] = (t > 0.f) ? (1.0f / sqrtf(t)) : 0.f;
  }
}

// Abf[i][j] = bf16( isq[i] * edge[i][j] * isq[j] ), grid (NN/1024, NN)
__global__ __launch_bounds__(256) void normalize_k(const float* __restrict__ edge,
                                                   const float* __restrict__ isq,
                                                   u16* __restrict__ Abf) {
  const int row = blockIdx.y;
  const int c4 = blockIdx.x * 256 + threadIdx.x;  // float4 index within row
  const size_t base = (size_t)row * NN;
  float4 e = ((const float4*)(edge + base))[c4];
  float4 q = ((const float4*)isq)[c4];
  const float ri = isq[row];
  ushort4 o;
  o.x = f32_to_bf16(ri * e.x * q.x);
  o.y = f32_to_bf16(ri * e.y * q.y);
  o.z = f32_to_bf16(ri * e.z * q.z);
  o.w = f32_to_bf16(ri * e.w * q.w);
  ((ushort4*)(Abf + base))[c4] = o;
}

__global__ __launch_bounds__(256) void f2bf_k(const float* __restrict__ in,
                                              u16* __restrict__ out, int n4) {
  int i = blockIdx.x * 256 + threadIdx.x;
  if (i >= n4) return;
  float4 v = ((const float4*)in)[i];
  ushort4 o;
  o.x = f32_to_bf16(v.x);
  o.y = f32_to_bf16(v.y);
  o.z = f32_to_bf16(v.z);
  o.w = f32_to_bf16(v.w);
  ((ushort4*)out)[i] = o;
}

// C[M,N] = act(A[M,K] * B[N,K]^T + bias[row]); A,B bf16 row-major, K%32==0,
// M,N%128==0. m97 structure: 128x128 tile, BK=32, 4 waves, 4x4 16x16x32 MFMA,
// global_load_lds width=16. If SPLIT: blockIdx.z = k-split index, each split
// covers Kper contiguous k, fp32 partials at Cout + z*M*N (RELU/BIAS/OBF16
// deferred to reduce_k).
template <bool RELU, bool BIAS, bool OBF16, bool SPLIT>
__global__ __launch_bounds__(256) void gemm_bt(const u16* __restrict__ A,
                                               const u16* __restrict__ B,
                                               const float* __restrict__ bias,
                                               void* __restrict__ Cout,
                                               const int M, const int N, const int K,
                                               const int Kper) {
  __shared__ __attribute__((aligned(16))) u16 As[128 * 32];
  __shared__ __attribute__((aligned(16))) u16 Bs[128 * 32];
  const int tid = threadIdx.x;
  const int wave = tid >> 6;
  const int lane = tid & 63;
  const size_t row0 = (size_t)blockIdx.y * 128;
  const size_t col0 = (size_t)blockIdx.x * 128;
  const int kbeg = SPLIT ? blockIdx.z * Kper : 0;
  const int klen = SPLIT ? Kper : K;
  const int wm = (wave >> 1) << 6;  // wave quadrant: 64x64
  const int wn = (wave & 1) << 6;

  f32x4 acc[4][4];
  const f32x4 zero = {0.f, 0.f, 0.f, 0.f};
#pragma unroll
  for (int i = 0; i < 4; ++i)
#pragma unroll
    for (int j = 0; j < 4; ++j) acc[i][j] = zero;

  // staging: flat element E = issue*2048 + wave*512 + lane*8; row=E/32 col=E%32
  const int e0 = wave * 512 + lane * 8;
  const int r0 = e0 >> 5;
  const int c0 = e0 & 31;
  const u16* Ab = A + row0 * K + (size_t)r0 * K + c0 + kbeg;
  const u16* Bb = B + col0 * K + (size_t)r0 * K + c0 + kbeg;
  u16* sA0 = &As[wave * 512];
  u16* sA1 = &As[2048 + wave * 512];
  u16* sB0 = &Bs[wave * 512];
  u16* sB1 = &Bs[2048 + wave * 512];
  const size_t K64 = (size_t)64 * K;

  const int fr = lane & 15;    // A: m, B: n  (lane&15)
  const int quad = lane >> 4;  // k = quad*8 + j
  const int aoff = (wm + fr) * 32 + quad * 8;
  const int boff = (wn + fr) * 32 + quad * 8;

  for (int kt = 0; kt < klen; kt += 32) {
    async_copy16(Ab + kt, sA0);
    async_copy16(Ab + K64 + kt, sA1);
    async_copy16(Bb + kt, sB0);
    async_copy16(Bb + K64 + kt, sB1);
    __syncthreads();  // drains vmcnt -> LDS visible
    bf16x8 af[4], bfr[4];
#pragma unroll
    for (int i = 0; i < 4; ++i) {
      af[i] = *(const bf16x8*)&As[aoff + i * 512];
      bfr[i] = *(const bf16x8*)&Bs[boff + i * 512];
    }
#pragma unroll
    for (int i = 0; i < 4; ++i)
#pragma unroll
      for (int j = 0; j < 4; ++j)
        acc[i][j] = __builtin_amdgcn_mfma_f32_16x16x32_bf16(af[i], bfr[j], acc[i][j], 0, 0, 0);
    __syncthreads();
  }

  // C/D layout (verified m89/m91): col = lane&15, row = (lane>>4)*4 + reg
  float* Pf = SPLIT ? ((float*)Cout + (size_t)blockIdx.z * M * N) : (float*)Cout;
#pragma unroll
  for (int i = 0; i < 4; ++i) {
#pragma unroll
    for (int r = 0; r < 4; ++r) {
      const size_t grow = row0 + wm + i * 16 + quad * 4 + r;
      float bv = 0.f;
      if (BIAS && !SPLIT) bv = bias[grow];
#pragma unroll
      for (int j = 0; j < 4; ++j) {
        const size_t gcol = col0 + wn + j * 16 + fr;
        float v = acc[i][j][r] + bv;
        if (SPLIT) {
          Pf[grow * N + gcol] = v;
        } else {
          if (RELU) v = fmaxf(v, 0.f);
          if (OBF16)
            ((u16*)Cout)[grow * N + gcol] = f32_to_bf16(v);
          else
            ((float*)Cout)[grow * N + gcol] = v;
        }
      }
    }
  }
}

// out = act( sum_s part[s] + bias ), vectorized float4 per thread.
template <bool RELU, bool BIAS, bool OBF16>
__global__ __launch_bounds__(256) void reduce_k(const float* __restrict__ part,
                                                const float* __restrict__ bias,
                                                void* __restrict__ out,
                                                const int M, const int N, const int ks) {
  const size_t MN4 = (size_t)M * N / 4;
  const size_t i4 = (size_t)blockIdx.x * 256 + threadIdx.x;
  if (i4 >= MN4) return;
  const float4* p4 = (const float4*)part;
  float4 s = p4[i4];
  for (int k = 1; k < ks; ++k) {
    float4 v = p4[(size_t)k * MN4 + i4];
    s.x += v.x; s.y += v.y; s.z += v.z; s.w += v.w;
  }
  if (BIAS) {
    const float b = bias[(int)((i4 * 4) / N)];
    s.x += b; s.y += b; s.z += b; s.w += b;
  }
  if (RELU) {
    s.x = fmaxf(s.x, 0.f); s.y = fmaxf(s.y, 0.f);
    s.z = fmaxf(s.z, 0.f); s.w = fmaxf(s.w, 0.f);
  }
  if (OBF16) {
    ushort4 o;
    o.x = f32_to_bf16(s.x); o.y = f32_to_bf16(s.y);
    o.z = f32_to_bf16(s.z); o.w = f32_to_bf16(s.w);
    ((ushort4*)out)[i4] = o;
  } else {
    ((float4*)out)[i4] = s;
  }
}

extern "C" void kernel_launch(void* const* d_in, const int* in_sizes, int n_in,
                              void* d_out, int out_size, void* d_ws, size_t ws_size,
                              hipStream_t stream) {
  const float* point = (const float*)d_in[0];
  const float* edge  = (const float*)d_in[1];
  const float* W1    = (const float*)d_in[2];
  const float* b1    = (const float*)d_in[3];
  const float* W2    = (const float*)d_in[4];
  const float* b2    = (const float*)d_in[5];
  float* out = (float*)d_out;

  char* ws = (char*)d_ws;
  size_t off = 0;
  auto alloc = [&](size_t bytes) -> void* {
    void* p = ws + off;
    off += (bytes + 255) & ~(size_t)255;
    return p;
  };
  float* isq  = (float*)alloc((size_t)NN * 4);
  u16* Abf    = (u16*)alloc((size_t)NN * NN * 2);        // 128 MB
  // scratch region (64 MB): pbf lives here early; split-K partials reuse it
  // serially (pbf dead after gemm1; each partial dead after its reduce).
  char* scratch = (char*)alloc((size_t)64 * 1024 * 1024);
  u16* w1bf   = (u16*)alloc((size_t)HIDC * INC * 2);     // 1 MB
  u16* w2bf   = (u16*)alloc((size_t)OUTC * HIDC * 2);    // 0.5 MB
  u16* Ht     = (u16*)alloc((size_t)HIDC * NN * 2);      // 16 MB  (h1^T)
  u16* h2     = (u16*)alloc((size_t)NN * HIDC * 2);      // 16 MB  (relu(A h1))
  u16* O1t    = (u16*)alloc((size_t)OUTC * NN * 2);      // 4 MB   (o1^T)
  const bool have_ws = off <= ws_size;  // deterministic -> graph-safe

  u16* pbf = (u16*)scratch;             // 8 MB, dead after gemm1
  float* part = (float*)scratch;        // split-K partials

  rowsum_k<<<NN, 256, 0, stream>>>(edge, isq);
  normalize_k<<<dim3(NN / 1024, NN), 256, 0, stream>>>(edge, isq, Abf);
  f2bf_k<<<(NN * INC / 4) / 256, 256, 0, stream>>>(point, pbf, NN * INC / 4);
  f2bf_k<<<(HIDC * INC / 4) / 256, 256, 0, stream>>>(W1, w1bf, HIDC * INC / 4);
  f2bf_k<<<(OUTC * HIDC / 4) / 256, 256, 0, stream>>>(W2, w2bf, OUTC * HIDC / 4);

  // Ht[c][n] = sum_k W1[c][k] point[n][k] + b1[c]   (h1^T, bf16) — 512 blocks
  gemm_bt<false, true, true, false><<<dim3(NN / 128, HIDC / 128), 256, 0, stream>>>(
      w1bf, pbf, b1, Ht, HIDC, NN, INC, INC);

  if (have_ws) {
    // h2 = relu(A @ h1): split-K 2 -> 1024 blocks of 128x128xK4096
    gemm_bt<false, false, false, true><<<dim3(HIDC / 128, NN / 128, 2), 256, 0, stream>>>(
        Abf, Ht, nullptr, part, NN, HIDC, NN, NN / 2);
    reduce_k<true, false, true><<<(NN * HIDC / 4) / 256, 256, 0, stream>>>(
        part, nullptr, h2, NN, HIDC, 2);
    // O1t = W2 @ h2^T + b2: split-K 4 -> 512 blocks of 128x128xK256
    gemm_bt<false, false, false, true><<<dim3(NN / 128, OUTC / 128, 4), 256, 0, stream>>>(
        w2bf, h2, nullptr, part, OUTC, NN, HIDC, HIDC / 4);
    reduce_k<false, true, true><<<(OUTC * NN / 4) / 256, 256, 0, stream>>>(
        part, b2, O1t, OUTC, NN, 4);
    // out = relu(A @ o1): split-K 8 -> 1024 blocks of 128x128xK1024
    gemm_bt<false, false, false, true><<<dim3(OUTC / 128, NN / 128, 8), 256, 0, stream>>>(
        Abf, O1t, nullptr, part, NN, OUTC, NN, NN / 8);
    reduce_k<true, false, false><<<(NN * OUTC / 4) / 256, 256, 0, stream>>>(
        part, nullptr, out, NN, OUTC, 8);
  } else {
    // fallback: round-1 non-split path (fits in ~174 MB)
    gemm_bt<true, false, true, false><<<dim3(HIDC / 128, NN / 128), 256, 0, stream>>>(
        Abf, Ht, nullptr, h2, NN, HIDC, NN, NN);
    gemm_bt<false, true, true, false><<<dim3(NN / 128, OUTC / 128), 256, 0, stream>>>(
        w2bf, h2, b2, O1t, OUTC, NN, HIDC, HIDC);
    gemm_bt<true, false, false, false><<<dim3(OUTC / 128, NN / 128), 256, 0, stream>>>(
        Abf, O1t, nullptr, out, NN, OUTC, NN, NN);
  }
}

// Round 3
// 769.692 us; speedup vs baseline: 1.1761x; 1.0931x over previous
//
#include <hip/hip_runtime.h>
#include <cstdint>

#define NN 8192
#define INC 512
#define HIDC 1024
#define OUTC 256

typedef unsigned short u16;
typedef __attribute__((ext_vector_type(8))) __bf16 bf16x8;
typedef __attribute__((ext_vector_type(4))) float f32x4;

__device__ __forceinline__ u16 f32_to_bf16(float f) {
  union { float f; unsigned u; } c; c.f = f;
  unsigned u = c.u;
  u += 0x7fffu + ((u >> 16) & 1u);   // round-to-nearest-even
  return (u16)(u >> 16);
}

// async global->LDS, 16B/lane. LDS dest is wave-uniform base + lane*16.
__device__ __forceinline__ void async_copy16(const void* g, void* l) {
  typedef __attribute__((address_space(1))) const char gch;
  typedef __attribute__((address_space(3))) char lch;
  __builtin_amdgcn_global_load_lds((gch*)(uint64_t)(uintptr_t)g,
                                   (lch*)(uint32_t)(uintptr_t)l, 16, 0, 0);
}

// deg[i] = sum_j edge[i][j]; isq[i] = deg>0 ? 1/sqrt(deg) : 0
__global__ __launch_bounds__(256) void rowsum_k(const float* __restrict__ edge,
                                                float* __restrict__ isq) {
  __shared__ float red[4];
  const int row = blockIdx.x;
  const float4* e4 = (const float4*)(edge + (size_t)row * NN);
  float s = 0.f;
#pragma unroll
  for (int it = 0; it < NN / 4 / 256; ++it) {
    float4 v = e4[it * 256 + threadIdx.x];
    s += (v.x + v.y) + (v.z + v.w);
  }
  for (int off = 32; off > 0; off >>= 1) s += __shfl_down(s, off, 64);
  if ((threadIdx.x & 63) == 0) red[threadIdx.x >> 6] = s;
  __syncthreads();
  if (threadIdx.x == 0) {
    float t = (red[0] + red[1]) + (red[2] + red[3]);
    isq[row] = (t > 0.f) ? (1.0f / sqrtf(t)) : 0.f;
  }
}

// Abf[i][j] = bf16( isq[i] * edge[i][j] * isq[j] ), grid (NN/1024, NN)
__global__ __launch_bounds__(256) void normalize_k(const float* __restrict__ edge,
                                                   const float* __restrict__ isq,
                                                   u16* __restrict__ Abf) {
  const int row = blockIdx.y;
  const int c4 = blockIdx.x * 256 + threadIdx.x;  // float4 index within row
  const size_t base = (size_t)row * NN;
  float4 e = ((const float4*)(edge + base))[c4];
  float4 q = ((const float4*)isq)[c4];
  const float ri = isq[row];
  ushort4 o;
  o.x = f32_to_bf16(ri * e.x * q.x);
  o.y = f32_to_bf16(ri * e.y * q.y);
  o.z = f32_to_bf16(ri * e.z * q.z);
  o.w = f32_to_bf16(ri * e.w * q.w);
  ((ushort4*)(Abf + base))[c4] = o;
}

__global__ __launch_bounds__(256) void f2bf_k(const float* __restrict__ in,
                                              u16* __restrict__ out, int n4) {
  int i = blockIdx.x * 256 + threadIdx.x;
  if (i >= n4) return;
  float4 v = ((const float4*)in)[i];
  ushort4 o;
  o.x = f32_to_bf16(v.x);
  o.y = f32_to_bf16(v.y);
  o.z = f32_to_bf16(v.z);
  o.w = f32_to_bf16(v.w);
  ((ushort4*)out)[i] = o;
}

// C[M,N] = act(A[M,K] * B[N,K]^T + bias[row]); A,B bf16 row-major, K%32==0,
// M,N%128==0. m97 structure: 128x128 tile, BK=32, 4 waves, 4x4 16x16x32 MFMA,
// global_load_lds width=16.
// SPLIT: blockIdx.z = k-split, fp32 partials at Cout + z*M*N, epilogue deferred.
// SWIZ (needs gridDim.y%8==0, gridDim.x*gridDim.y%8==0): remap blocks so all
// blocks sharing an A row-panel (same y) get the same linear-id%8 -> same XCD
// under round-robin dispatch; A panel then lives in that XCD's L2 and is
// reused gridDim.x times instead of being re-fetched from HBM per XCD.
template <bool RELU, bool BIAS, bool OBF16, bool SPLIT, bool SWIZ>
__global__ __launch_bounds__(256) void gemm_bt(const u16* __restrict__ A,
                                               const u16* __restrict__ B,
                                               const float* __restrict__ bias,
                                               void* __restrict__ Cout,
                                               const int M, const int N, const int K,
                                               const int Kper) {
  __shared__ __attribute__((aligned(16))) u16 As[128 * 32];
  __shared__ __attribute__((aligned(16))) u16 Bs[128 * 32];
  const int tid = threadIdx.x;
  const int wave = tid >> 6;
  const int lane = tid & 63;

  int bx = blockIdx.x, by = blockIdx.y;
  if (SWIZ) {
    const int i2 = bx + gridDim.x * by;
    const int xcd = i2 & 7;
    const int slot = i2 >> 3;
    const int ypg = gridDim.y >> 3;  // y-panels per XCD
    by = xcd * ypg + (slot % ypg);
    bx = slot / ypg;
  }
  const size_t row0 = (size_t)by * 128;
  const size_t col0 = (size_t)bx * 128;
  const int kbeg = SPLIT ? blockIdx.z * Kper : 0;
  const int klen = SPLIT ? Kper : K;
  const int wm = (wave >> 1) << 6;  // wave quadrant: 64x64
  const int wn = (wave & 1) << 6;

  f32x4 acc[4][4];
  const f32x4 zero = {0.f, 0.f, 0.f, 0.f};
#pragma unroll
  for (int i = 0; i < 4; ++i)
#pragma unroll
    for (int j = 0; j < 4; ++j) acc[i][j] = zero;

  // staging: flat element E = issue*2048 + wave*512 + lane*8; row=E/32 col=E%32
  const int e0 = wave * 512 + lane * 8;
  const int r0 = e0 >> 5;
  const int c0 = e0 & 31;
  const u16* Ab = A + row0 * K + (size_t)r0 * K + c0 + kbeg;
  const u16* Bb = B + col0 * K + (size_t)r0 * K + c0 + kbeg;
  u16* sA0 = &As[wave * 512];
  u16* sA1 = &As[2048 + wave * 512];
  u16* sB0 = &Bs[wave * 512];
  u16* sB1 = &Bs[2048 + wave * 512];
  const size_t K64 = (size_t)64 * K;

  const int fr = lane & 15;    // A: m, B: n  (lane&15)
  const int quad = lane >> 4;  // k = quad*8 + j
  const int aoff = (wm + fr) * 32 + quad * 8;
  const int boff = (wn + fr) * 32 + quad * 8;

  for (int kt = 0; kt < klen; kt += 32) {
    async_copy16(Ab + kt, sA0);
    async_copy16(Ab + K64 + kt, sA1);
    async_copy16(Bb + kt, sB0);
    async_copy16(Bb + K64 + kt, sB1);
    __syncthreads();  // drains vmcnt -> LDS visible
    bf16x8 af[4], bfr[4];
#pragma unroll
    for (int i = 0; i < 4; ++i) {
      af[i] = *(const bf16x8*)&As[aoff + i * 512];
      bfr[i] = *(const bf16x8*)&Bs[boff + i * 512];
    }
#pragma unroll
    for (int i = 0; i < 4; ++i)
#pragma unroll
      for (int j = 0; j < 4; ++j)
        acc[i][j] = __builtin_amdgcn_mfma_f32_16x16x32_bf16(af[i], bfr[j], acc[i][j], 0, 0, 0);
    __syncthreads();
  }

  // C/D layout (verified m89/m91): col = lane&15, row = (lane>>4)*4 + reg
  float* Pf = SPLIT ? ((float*)Cout + (size_t)blockIdx.z * M * N) : (float*)Cout;
#pragma unroll
  for (int i = 0; i < 4; ++i) {
#pragma unroll
    for (int r = 0; r < 4; ++r) {
      const size_t grow = row0 + wm + i * 16 + quad * 4 + r;
      float bv = 0.f;
      if (BIAS && !SPLIT) bv = bias[grow];
#pragma unroll
      for (int j = 0; j < 4; ++j) {
        const size_t gcol = col0 + wn + j * 16 + fr;
        float v = acc[i][j][r] + bv;
        if (SPLIT) {
          Pf[grow * N + gcol] = v;
        } else {
          if (RELU) v = fmaxf(v, 0.f);
          if (OBF16)
            ((u16*)Cout)[grow * N + gcol] = f32_to_bf16(v);
          else
            ((float*)Cout)[grow * N + gcol] = v;
        }
      }
    }
  }
}

// out = act( sum_s part[s] + bias ), vectorized float4 per thread.
template <bool RELU, bool BIAS, bool OBF16>
__global__ __launch_bounds__(256) void reduce_k(const float* __restrict__ part,
                                                const float* __restrict__ bias,
                                                void* __restrict__ out,
                                                const int M, const int N, const int ks) {
  const size_t MN4 = (size_t)M * N / 4;
  const size_t i4 = (size_t)blockIdx.x * 256 + threadIdx.x;
  if (i4 >= MN4) return;
  const float4* p4 = (const float4*)part;
  float4 s = p4[i4];
  for (int k = 1; k < ks; ++k) {
    float4 v = p4[(size_t)k * MN4 + i4];
    s.x += v.x; s.y += v.y; s.z += v.z; s.w += v.w;
  }
  if (BIAS) {
    const float b = bias[(int)((i4 * 4) / N)];
    s.x += b; s.y += b; s.z += b; s.w += b;
  }
  if (RELU) {
    s.x = fmaxf(s.x, 0.f); s.y = fmaxf(s.y, 0.f);
    s.z = fmaxf(s.z, 0.f); s.w = fmaxf(s.w, 0.f);
  }
  if (OBF16) {
    ushort4 o;
    o.x = f32_to_bf16(s.x); o.y = f32_to_bf16(s.y);
    o.z = f32_to_bf16(s.z); o.w = f32_to_bf16(s.w);
    ((ushort4*)out)[i4] = o;
  } else {
    ((float4*)out)[i4] = s;
  }
}

extern "C" void kernel_launch(void* const* d_in, const int* in_sizes, int n_in,
                              void* d_out, int out_size, void* d_ws, size_t ws_size,
                              hipStream_t stream) {
  const float* point = (const float*)d_in[0];
  const float* edge  = (const float*)d_in[1];
  const float* W1    = (const float*)d_in[2];
  const float* b1    = (const float*)d_in[3];
  const float* W2    = (const float*)d_in[4];
  const float* b2    = (const float*)d_in[5];
  float* out = (float*)d_out;

  char* ws = (char*)d_ws;
  size_t off = 0;
  auto alloc = [&](size_t bytes) -> void* {
    void* p = ws + off;
    off += (bytes + 255) & ~(size_t)255;
    return p;
  };
  float* isq  = (float*)alloc((size_t)NN * 4);
  u16* Abf    = (u16*)alloc((size_t)NN * NN * 2);        // 128 MB
  // scratch (64 MB): pbf early; split-K partials reuse serially.
  char* scratch = (char*)alloc((size_t)64 * 1024 * 1024);
  u16* w1bf   = (u16*)alloc((size_t)HIDC * INC * 2);     // 1 MB
  u16* w2bf   = (u16*)alloc((size_t)OUTC * HIDC * 2);    // 0.5 MB
  u16* Ht     = (u16*)alloc((size_t)HIDC * NN * 2);      // 16 MB  (h1^T)
  u16* h2     = (u16*)alloc((size_t)NN * HIDC * 2);      // 16 MB  (relu(A h1))
  u16* O1t    = (u16*)alloc((size_t)OUTC * NN * 2);      // 4 MB   (o1^T)
  const bool have_ws = off <= ws_size;  // deterministic -> graph-safe

  u16* pbf = (u16*)scratch;             // 8 MB, dead after gemm1
  float* part = (float*)scratch;        // split-K partials

  rowsum_k<<<NN, 256, 0, stream>>>(edge, isq);
  normalize_k<<<dim3(NN / 1024, NN), 256, 0, stream>>>(edge, isq, Abf);
  f2bf_k<<<(NN * INC / 4) / 256, 256, 0, stream>>>(point, pbf, NN * INC / 4);
  f2bf_k<<<(HIDC * INC / 4) / 256, 256, 0, stream>>>(W1, w1bf, HIDC * INC / 4);
  f2bf_k<<<(OUTC * HIDC / 4) / 256, 256, 0, stream>>>(W2, w2bf, OUTC * HIDC / 4);

  // Ht[c][n] = sum_k W1[c][k] point[n][k] + b1[c]   (h1^T, bf16) — 512 blocks
  gemm_bt<false, true, true, false, false><<<dim3(NN / 128, HIDC / 128), 256, 0, stream>>>(
      w1bf, pbf, b1, Ht, HIDC, NN, INC, INC);

  // h2 = relu(A @ h1): non-split (R2 showed split-K gains nothing here),
  // XCD swizzle for A-panel L2 reuse (8 N-tiles share each A row-panel).
  gemm_bt<true, false, true, false, true><<<dim3(HIDC / 128, NN / 128), 256, 0, stream>>>(
      Abf, Ht, nullptr, h2, NN, HIDC, NN, NN);

  if (have_ws) {
    // O1t = W2 @ h2^T + b2: split-K 4 -> 512 blocks of 128x128xK256
    gemm_bt<false, false, false, true, false><<<dim3(NN / 128, OUTC / 128, 4), 256, 0, stream>>>(
        w2bf, h2, nullptr, part, OUTC, NN, HIDC, HIDC / 4);
    reduce_k<false, true, true><<<(OUTC * NN / 4) / 256, 256, 0, stream>>>(
        part, b2, O1t, OUTC, NN, 4);
    // out = relu(A @ o1): split-K 8 -> 1024 blocks of 128x128xK1024, swizzled
    gemm_bt<false, false, false, true, true><<<dim3(OUTC / 128, NN / 128, 8), 256, 0, stream>>>(
        Abf, O1t, nullptr, part, NN, OUTC, NN, NN / 8);
    reduce_k<true, false, false><<<(NN * OUTC / 4) / 256, 256, 0, stream>>>(
        part, nullptr, out, NN, OUTC, 8);
  } else {
    // fallback: non-split path
    gemm_bt<false, true, true, false, false><<<dim3(NN / 128, OUTC / 128), 256, 0, stream>>>(
        w2bf, h2, b2, O1t, OUTC, NN, HIDC, HIDC);
    gemm_bt<true, false, false, false, true><<<dim3(OUTC / 128, NN / 128), 256, 0, stream>>>(
        Abf, O1t, nullptr, out, NN, OUTC, NN, NN);
  }
}